// Round 2
// baseline (430.959 us; speedup 1.0000x reference)
//
#include <hip/hip_runtime.h>

// TargetAttention: B=4096, L=200, D=64, fp32.
// out[b] = (softmax_l( (tk[b]@Wt^T@Wi) . ik[b,l] / 8 + maskbias ) . iv[b,l,:]) @ Wv^T
// One block of 256 threads per batch row. Memory-bound: streams ik+iv (419 MB).
// R2: phase-1 score pass restructured to fully-coalesced loads (ik4[it*256+t])
//     + 16-lane shuffle reduce, replacing the 256B-strided per-row loads that
//     made R1 transaction-bound (1.5 TB/s HBM, 6% VALU).

#define B_ 4096
#define L_ 200
#define D_ 64

__global__ __launch_bounds__(256) void ta_kernel(
    const float* __restrict__ tk,    // [B,D]
    const float* __restrict__ ik,    // [B,L,D]
    const float* __restrict__ iv,    // [B,L,D]
    const int*   __restrict__ mask,  // [B,L]
    const float* __restrict__ Wt,    // [D,D]
    const float* __restrict__ Wi,    // [D,D]
    const float* __restrict__ Wv,    // [D,D]
    float* __restrict__ out)         // [B,D]
{
  const int t = threadIdx.x;
  const int b = blockIdx.x;
  const int c  = t & 15;   // float4 chunk of D  (d in [4c, 4c+4))
  const int rg = t >> 4;   // row group 0..15

  __shared__ float q_s[D_];
  __shared__ float qt_s[D_];
  __shared__ float bias_s[L_];
  __shared__ float sc[L_];
  __shared__ float red[8];
  __shared__ float vred[256 * 4];
  __shared__ float sv[D_];

  // ---- stage mask bias (coalesced) ----
  if (t < L_) {
    int m = mask[(size_t)b * L_ + t];
    bias_s[t] = m ? 0.0f : -1e8f;
  }

  // ---- phase 0: qt = (tk[b] @ Wt^T) @ Wi  (weights are L1/L2-hot) ----
  if (t < D_) {
    const float4* tkb4 = (const float4*)(tk + (size_t)b * D_);
    const float4* Wt4  = (const float4*)Wt;
    float a = 0.f;
#pragma unroll
    for (int j = 0; j < 16; ++j) {
      float4 w = Wt4[t * 16 + j];
      float4 x = tkb4[j];               // broadcast, L1-hot
      a += w.x * x.x + w.y * x.y + w.z * x.z + w.w * x.w;
    }
    q_s[t] = a;
  }
  __syncthreads();
  if (t < D_) {
    float a = 0.f;
#pragma unroll
    for (int e = 0; e < D_; ++e) a += q_s[e] * Wi[e * D_ + t];  // coalesced over t
    qt_s[t] = a;
  }
  __syncthreads();

  // ---- phase 1: scores, fully coalesced (same layout as phase 2) ----
  // thread (rg,c) loads ik4[it*256 + t]; 16-lane shuffle-reduce per row.
  const float4* ik4 = (const float4*)(ik + (size_t)b * (L_ * D_));
  const float4* q4  = (const float4*)qt_s;
  const float4 qc = q4[c];              // this thread's fixed q chunk
#pragma unroll
  for (int it = 0; it < 13; ++it) {
    int row = it * 16 + rg;
    float p = 0.f;
    if (row < L_) {
      float4 kv = ik4[it * 256 + t];    // contiguous 4 KB per iteration
      p = kv.x * qc.x + kv.y * qc.y + kv.z * qc.z + kv.w * qc.w;
    }
    // reduce over the 16 chunk lanes (aligned 16-lane groups within wave64)
    p += __shfl_xor(p, 8, 64);
    p += __shfl_xor(p, 4, 64);
    p += __shfl_xor(p, 2, 64);
    p += __shfl_xor(p, 1, 64);
    if (c == 0 && row < L_) sc[row] = p * 0.125f + bias_s[row];
  }
  __syncthreads();

  // ---- softmax over L=200 (wave shuffle + LDS combine) ----
  float v = (t < L_) ? sc[t] : -3.0e38f;
#pragma unroll
  for (int off = 32; off >= 1; off >>= 1)
    v = fmaxf(v, __shfl_xor(v, off, 64));
  if ((t & 63) == 0) red[t >> 6] = v;
  __syncthreads();
  float mx = fmaxf(fmaxf(red[0], red[1]), fmaxf(red[2], red[3]));
  float ex = (t < L_) ? expf(sc[t] - mx) : 0.f;
  float s = ex;
#pragma unroll
  for (int off = 32; off >= 1; off >>= 1)
    s += __shfl_xor(s, off, 64);
  if ((t & 63) == 0) red[4 + (t >> 6)] = s;
  __syncthreads();
  float tot = red[4] + red[5] + red[6] + red[7];
  if (t < L_) sc[t] = ex / tot;   // normalized weights
  __syncthreads();

  // ---- phase 2: sv[d] = sum_l w[l] * iv[b,l,d]  (coalesced 4KB/iter) ----
  const float4* iv4 = (const float4*)(iv + (size_t)b * (L_ * D_));
  float4 acc = make_float4(0.f, 0.f, 0.f, 0.f);
#pragma unroll
  for (int it = 0; it < 13; ++it) {
    int row = it * 16 + rg;
    if (row < L_) {
      float w = sc[row];
      float4 vv = iv4[it * 256 + t];   // contiguous
      acc.x += w * vv.x; acc.y += w * vv.y;
      acc.z += w * vv.z; acc.w += w * vv.w;
    }
  }
  ((float4*)vred)[t] = acc;
  __syncthreads();
  if (t < D_) {
    float a = 0.f;
#pragma unroll
    for (int rg2 = 0; rg2 < 16; ++rg2) a += vred[rg2 * 64 + t];  // 2 lanes/bank: free
    sv[t] = a;
  }
  __syncthreads();

  // ---- phase 3: out[b,e] = sv @ Wv^T  (Wv is L1-hot) ----
  if (t < D_) {
    const float4* Wv4 = (const float4*)Wv;
    const float4* sv4 = (const float4*)sv;
    float a = 0.f;
#pragma unroll
    for (int cc = 0; cc < 16; ++cc) {
      float4 w4 = Wv4[t * 16 + cc];
      float4 s4 = sv4[cc];
      a += w4.x * s4.x + w4.y * s4.y + w4.z * s4.z + w4.w * s4.w;
    }
    out[(size_t)b * D_ + t] = a;
  }
}

extern "C" void kernel_launch(void* const* d_in, const int* in_sizes, int n_in,
                              void* d_out, int out_size, void* d_ws, size_t ws_size,
                              hipStream_t stream) {
  const float* tk   = (const float*)d_in[0];  // target_key  [B,D]
  const float* ik   = (const float*)d_in[1];  // item_keys   [B,L,D]
  const float* iv   = (const float*)d_in[2];  // item_values [B,L,D]
  const int*   mask = (const int*)  d_in[3];  // mask        [B,L]
  const float* Wt   = (const float*)d_in[4];  // W_target    [D,D]
  const float* Wi   = (const float*)d_in[5];  // W_item      [D,D]
  const float* Wv   = (const float*)d_in[6];  // W_value     [D,D]
  float* out = (float*)d_out;                 // [B,D]

  ta_kernel<<<B_, 256, 0, stream>>>(tk, ik, iv, mask, Wt, Wi, Wv, out);
}

// Round 3
// 415.567 us; speedup vs baseline: 1.0370x; 1.0370x over previous
//
#include <hip/hip_runtime.h>

// TargetAttention: B=4096, L=200, D=64, fp32.
// out[b] = (softmax_l( (tk[b]@Wt^T@Wi) . ik[b,l] / 8 + maskbias ) . iv[b,l,:]) @ Wv^T
// One block of 256 threads per batch row. Memory-bound: streams ik+iv (419 MB).
// R3: MLP fix. R1/R2 both had VGPR=36 -> compiler kept only ~2-3 loads in
//     flight (latency-bound at 4.9 B/cyc/CU, HBM 18%, VALU 7%). Now all 26
//     float4 stream loads (13 ik + 13 iv) are issued up-front into explicit
//     register arrays; __launch_bounds__(256,3) allows ~170 VGPRs. V stays
//     in registers across softmax; phase 2 is pure FMA.

#define B_ 4096
#define L_ 200
#define D_ 64

__global__ __launch_bounds__(256, 3) void ta_kernel(
    const float* __restrict__ tk,    // [B,D]
    const float* __restrict__ ik,    // [B,L,D]
    const float* __restrict__ iv,    // [B,L,D]
    const int*   __restrict__ mask,  // [B,L]
    const float* __restrict__ Wt,    // [D,D]
    const float* __restrict__ Wi,    // [D,D]
    const float* __restrict__ Wv,    // [D,D]
    float* __restrict__ out)         // [B,D]
{
  const int t = threadIdx.x;
  const int b = blockIdx.x;
  const int c  = t & 15;   // float4 chunk of D  (d in [4c, 4c+4))
  const int rg = t >> 4;   // row group 0..15

  __shared__ float q_s[D_];
  __shared__ float qt_s[D_];
  __shared__ float bias_s[L_];
  __shared__ float sc[208];          // padded to 13*16, pad zeroed
  __shared__ float red[8];
  __shared__ float vred[256 * 4];
  __shared__ float sv[D_];

  // ---- stage mask bias (coalesced) ----
  if (t < L_) {
    int m = mask[(size_t)b * L_ + t];
    bias_s[t] = m ? 0.0f : -1e8f;
  }

  // ---- phase 0: qt = (tk[b] @ Wt^T) @ Wi  (weights L1/L2-hot; BEFORE the
  //      big load issue so its barriers don't drain the stream) ----
  if (t < D_) {
    const float4* tkb4 = (const float4*)(tk + (size_t)b * D_);
    const float4* Wt4  = (const float4*)Wt;
    float a = 0.f;
#pragma unroll
    for (int j = 0; j < 16; ++j) {
      float4 w = Wt4[t * 16 + j];
      float4 x = tkb4[j];
      a += w.x * x.x + w.y * x.y + w.z * x.z + w.w * x.w;
    }
    q_s[t] = a;
  }
  __syncthreads();
  if (t < D_) {
    float a = 0.f;
#pragma unroll
    for (int e = 0; e < D_; ++e) a += q_s[e] * Wi[e * D_ + t];  // coalesced over t
    qt_s[t] = a;
  }
  __syncthreads();

  // ---- issue the entire stream: 13 K + 13 V float4 loads per thread ----
  const float4* ik4 = (const float4*)(ik + (size_t)b * (L_ * D_));
  const float4* iv4 = (const float4*)(iv + (size_t)b * (L_ * D_));
  float4 K[13], V[13];
#pragma unroll
  for (int it = 0; it < 12; ++it) K[it] = ik4[it * 256 + t];
  K[12] = (192 + rg < L_) ? ik4[12 * 256 + t] : make_float4(0.f, 0.f, 0.f, 0.f);
#pragma unroll
  for (int it = 0; it < 12; ++it) V[it] = iv4[it * 256 + t];
  V[12] = (192 + rg < L_) ? iv4[12 * 256 + t] : make_float4(0.f, 0.f, 0.f, 0.f);

  // ---- phase 1: scores from K regs, 16-lane shuffle reduce ----
  const float4 qc = ((const float4*)qt_s)[c];
#pragma unroll
  for (int it = 0; it < 13; ++it) {
    float4 kv = K[it];
    float p = kv.x * qc.x + kv.y * qc.y + kv.z * qc.z + kv.w * qc.w;
    p += __shfl_xor(p, 8, 64);
    p += __shfl_xor(p, 4, 64);
    p += __shfl_xor(p, 2, 64);
    p += __shfl_xor(p, 1, 64);
    int row = it * 16 + rg;
    if (c == 0 && row < L_) sc[row] = p * 0.125f + bias_s[row];
  }
  __syncthreads();   // drains vmcnt(0): the stream wait (V completes here too)

  // ---- softmax over L=200 (wave shuffle + LDS combine) ----
  float v = (t < L_) ? sc[t] : -3.0e38f;
#pragma unroll
  for (int off = 32; off >= 1; off >>= 1)
    v = fmaxf(v, __shfl_xor(v, off, 64));
  if ((t & 63) == 0) red[t >> 6] = v;
  __syncthreads();
  float mx = fmaxf(fmaxf(red[0], red[1]), fmaxf(red[2], red[3]));
  float ex = (t < L_) ? expf(sc[t] - mx) : 0.f;
  float s = ex;
#pragma unroll
  for (int off = 32; off >= 1; off >>= 1)
    s += __shfl_xor(s, off, 64);
  if ((t & 63) == 0) red[4 + (t >> 6)] = s;
  __syncthreads();
  float tot = red[4] + red[5] + red[6] + red[7];
  if (t < L_)      sc[t] = ex / tot;   // normalized weights
  else if (t < 208) sc[t] = 0.f;       // zero the pad rows
  __syncthreads();

  // ---- phase 2: weighted sum from V regs (pure FMA) ----
  float4 acc = make_float4(0.f, 0.f, 0.f, 0.f);
#pragma unroll
  for (int it = 0; it < 13; ++it) {
    float w = sc[it * 16 + rg];        // pad rows have w=0
    acc.x += w * V[it].x; acc.y += w * V[it].y;
    acc.z += w * V[it].z; acc.w += w * V[it].w;
  }
  ((float4*)vred)[t] = acc;
  __syncthreads();
  if (t < D_) {
    float a = 0.f;
#pragma unroll
    for (int rg2 = 0; rg2 < 16; ++rg2) a += vred[rg2 * 64 + t];  // 2 lanes/bank: free
    sv[t] = a;
  }
  __syncthreads();

  // ---- phase 3: out[b,e] = sv @ Wv^T  (Wv is L1-hot) ----
  if (t < D_) {
    const float4* Wv4 = (const float4*)Wv;
    const float4* sv4 = (const float4*)sv;
    float a = 0.f;
#pragma unroll
    for (int cc = 0; cc < 16; ++cc) {
      float4 w4 = Wv4[t * 16 + cc];
      float4 s4 = sv4[cc];
      a += w4.x * s4.x + w4.y * s4.y + w4.z * s4.z + w4.w * s4.w;
    }
    out[(size_t)b * D_ + t] = a;
  }
}

extern "C" void kernel_launch(void* const* d_in, const int* in_sizes, int n_in,
                              void* d_out, int out_size, void* d_ws, size_t ws_size,
                              hipStream_t stream) {
  const float* tk   = (const float*)d_in[0];  // target_key  [B,D]
  const float* ik   = (const float*)d_in[1];  // item_keys   [B,L,D]
  const float* iv   = (const float*)d_in[2];  // item_values [B,L,D]
  const int*   mask = (const int*)  d_in[3];  // mask        [B,L]
  const float* Wt   = (const float*)d_in[4];  // W_target    [D,D]
  const float* Wi   = (const float*)d_in[5];  // W_item      [D,D]
  const float* Wv   = (const float*)d_in[6];  // W_value     [D,D]
  float* out = (float*)d_out;                 // [B,D]

  ta_kernel<<<B_, 256, 0, stream>>>(tk, ik, iv, mask, Wt, Wi, Wv, out);
}